// Round 1
// baseline (39.145 us; speedup 1.0000x reference)
//
#include <hip/hip_runtime.h>
#include <float.h>

// Problem constants (from reference)
#define BB 32
#define CC 128
#define HH 64
#define WW 64
// out: [B, C, 32, 16]  -> 2,097,152 f32 elements

__global__ __launch_bounds__(256) void roipool_kernel(
    const float* __restrict__ x,   // [B,C,H,W]
    const float* __restrict__ lm,  // [B,16]
    float* __restrict__ out)       // [B,C,32,16]
{
    int tid = blockIdx.x * 256 + threadIdx.x;

    int col = tid & 15;          // 0..15
    int row = (tid >> 4) & 31;   // 0..31
    int c   = (tid >> 9) & 127;  // 0..127
    int b   = tid >> 16;         // 0..31

    int lmi = ((row >> 3) << 1) + (col >> 3);  // landmark index 0..7
    int pi  = row & 7;                         // pooled-row within bin grid
    int pj  = col & 7;                         // pooled-col within bin grid

    float x0 = lm[b * 16 + 2 * lmi];
    float y0 = lm[b * 16 + 2 * lmi + 1];
    bool visible = (x0 > 0.0f) || (y0 > 0.0f);

    // torchvision column-swap semantics faithfully reproduced:
    // rois = (b, x1, x2, y1, y2) read as (b, start_w, start_h, end_w, end_h)
    int fx = (int)floorf(x0 * 0.25f);   // floor(x0*SCALE), exact-integer float -> int
    int fy = (int)floorf(y0 * 0.25f);
    int start_w = fx - 7;   // x1
    int start_h = fx;       // x2 = x1 + 7
    int end_w   = fy - 7;   // y1
    int end_h   = fy;       // y2 = y1 + 7

    float roi_w = fmaxf((float)(end_w - start_w + 1), 1.0f);
    float roi_h = fmaxf((float)(end_h - start_h + 1), 1.0f);
    float bin_h = roi_h * 0.125f;   // exact /8
    float bin_w = roi_w * 0.125f;

    int hs = min(max((int)floorf((float)pi * bin_h) + start_h, 0), HH);
    int he = min(max((int)ceilf((float)(pi + 1) * bin_h) + start_h, 0), HH);
    int ws = min(max((int)floorf((float)pj * bin_w) + start_w, 0), WW);
    int we = min(max((int)ceilf((float)(pj + 1) * bin_w) + start_w, 0), WW);

    bool empty = (he <= hs) || (we <= ws);

    float m = -FLT_MAX;
    const float* __restrict__ xp = x + (size_t)(b * CC + c) * (HH * WW);
    for (int h = hs; h < he; ++h) {
        const float* __restrict__ rp = xp + h * WW;
        for (int w = ws; w < we; ++w) {
            m = fmaxf(m, rp[w]);
        }
    }

    out[tid] = (empty || !visible) ? 0.0f : m;
}

extern "C" void kernel_launch(void* const* d_in, const int* in_sizes, int n_in,
                              void* d_out, int out_size, void* d_ws, size_t ws_size,
                              hipStream_t stream) {
    const float* x  = (const float*)d_in[0];
    const float* lm = (const float*)d_in[1];
    float* out = (float*)d_out;

    int total = BB * CC * 32 * 16;           // 2,097,152
    int blocks = total / 256;                // 8192
    roipool_kernel<<<blocks, 256, 0, stream>>>(x, lm, out);
}